// Round 3
// baseline (883.677 us; speedup 1.0000x reference)
//
#include <hip/hip_runtime.h>
#include <math.h>

#define FIN 512
#define FH 16
#define FOUT 40
#define RANGE 128        // dst nodes per bucket
#define RSH 7
#define NB_MAX 1024      // supports n <= 131072 (also the 17-bit src pack limit)
#define SRC_BITS 17
#define SRC_MASK 0x1FFFF
#define BCHUNK 4096      // edges per bin_k block
#define HCHUNK 16384     // edges per histA block

// ---------- bucket histogram: bcnt[b] = #edges with dst in bucket b ----------
__global__ __launch_bounds__(256) void histA_k(const int* __restrict__ dst, int E, int NB,
                                               unsigned* __restrict__ bcnt) {
  __shared__ unsigned h[NB_MAX];
  for (int b = threadIdx.x; b < NB; b += 256) h[b] = 0;
  __syncthreads();
  const int base = blockIdx.x * HCHUNK;
  const int cn = min(HCHUNK, E - base);
  for (int u = threadIdx.x; u < cn; u += 256)
    atomicAdd(&h[((unsigned)dst[base + u]) >> RSH], 1u);
  __syncthreads();
  for (int b = threadIdx.x; b < NB; b += 256) {
    unsigned c = h[b];
    if (c) atomicAdd(&bcnt[b], c);
  }
}

// ---------- exclusive scan of bucket counts (NB <= 1024, one block) ----------
__global__ __launch_bounds__(1024) void scanB_k(const unsigned* __restrict__ bcnt, int NB,
                                                unsigned* __restrict__ boff,
                                                unsigned* __restrict__ bcur) {
  __shared__ unsigned ws[16];
  const int t = threadIdx.x, lane = t & 63, wid = t >> 6;
  unsigned v = (t < NB) ? bcnt[t] : 0;
  unsigned incl = v;
#pragma unroll
  for (int d = 1; d < 64; d <<= 1) {
    unsigned o = __shfl_up(incl, d);
    if (lane >= d) incl += o;
  }
  if (lane == 63) ws[wid] = incl;
  __syncthreads();
  unsigned woff = 0, tot = 0;
#pragma unroll
  for (int w = 0; w < 16; ++w) {
    unsigned s = ws[w];
    if (w < wid) woff += s;
    tot += s;
  }
  unsigned ex = woff + incl - v;
  if (t < NB) { boff[t] = ex; bcur[t] = ex; }
  if (t == 0) boff[NB] = tot;
}

// ---------- bin edges by bucket: chunk-local counting sort, coalesced flush ----------
__global__ __launch_bounds__(256) void bin_k(const int* __restrict__ src,
                                             const int* __restrict__ dst, int E, int NB,
                                             unsigned* __restrict__ bcur,
                                             unsigned* __restrict__ bins) {
  __shared__ unsigned hist[NB_MAX];
  __shared__ unsigned excl[NB_MAX];
  __shared__ unsigned gbase[NB_MAX];
  __shared__ unsigned lcur[NB_MAX];
  __shared__ unsigned stage[BCHUNK];
  __shared__ unsigned short sbkt[BCHUNK];
  __shared__ unsigned wtot[4];
  const int t = threadIdx.x, lane = t & 63, wid = t >> 6;
  for (int b = t; b < NB; b += 256) hist[b] = 0;
  __syncthreads();
  const int base = blockIdx.x * BCHUNK;
  const int cn = min(BCHUNK, E - base);
  for (int u = t; u < cn; u += 256)
    atomicAdd(&hist[((unsigned)dst[base + u]) >> RSH], 1u);
  __syncthreads();
  // block-wide exclusive scan of hist[0..NB)
  unsigned loc[4], s = 0;
#pragma unroll
  for (int j = 0; j < 4; ++j) {
    int idx = t * 4 + j;
    loc[j] = s;
    s += (idx < NB) ? hist[idx] : 0;
  }
  unsigned incl = s;
#pragma unroll
  for (int d = 1; d < 64; d <<= 1) {
    unsigned o = __shfl_up(incl, d);
    if (lane >= d) incl += o;
  }
  if (lane == 63) wtot[wid] = incl;
  __syncthreads();
  unsigned woff = 0;
  for (int w = 0; w < wid; ++w) woff += wtot[w];
  unsigned tex = woff + incl - s;
#pragma unroll
  for (int j = 0; j < 4; ++j) {
    int idx = t * 4 + j;
    if (idx < NB) excl[idx] = tex + loc[j];
  }
  __syncthreads();
  for (int b = t; b < NB; b += 256) {
    unsigned c = hist[b];
    gbase[b] = c ? atomicAdd(&bcur[b], c) : 0u;
    lcur[b] = excl[b];
  }
  __syncthreads();
  for (int u = t; u < cn; u += 256) {
    int e = base + u;
    unsigned d = (unsigned)dst[e];
    unsigned bkt = d >> RSH;
    unsigned pk = ((unsigned)src[e]) | ((d & (RANGE - 1)) << SRC_BITS);
    unsigned lr = atomicAdd(&lcur[bkt], 1u);
    stage[lr] = pk;
    sbkt[lr] = (unsigned short)bkt;
  }
  __syncthreads();
  for (int u = t; u < cn; u += 256) {
    unsigned bkt = sbkt[u];
    bins[gbase[bkt] + (u - excl[bkt])] = stage[u];
  }
}

// ---------- per-node degree -> dinv, from binned edges (LDS histogram) ----------
__global__ __launch_bounds__(256) void deg_k(const unsigned* __restrict__ boff,
                                             const unsigned* __restrict__ bins, int n,
                                             float* __restrict__ dinv) {
  __shared__ unsigned dh[RANGE];
  const int t = threadIdx.x, b = blockIdx.x;
  if (t < RANGE) dh[t] = 0;
  __syncthreads();
  const unsigned jb = boff[b], je = boff[b + 1];
  for (unsigned j = jb + t; j < je; j += 256) atomicAdd(&dh[bins[j] >> SRC_BITS], 1u);
  __syncthreads();
  const int i = b * RANGE + t;
  if (t < RANGE && i < n) dinv[i] = rsqrtf((float)dh[t] + 1.0f);
}

// ---------------- hs1 = (x @ W1) * dinv[row] ----------------
__global__ __launch_bounds__(256) void gemm1_k(const float* __restrict__ x,
                                               const float* __restrict__ W1,
                                               const float* __restrict__ dinv, int n,
                                               float* __restrict__ hs1) {
  __shared__ float w1s[FIN * FH];  // 32 KiB
  for (int idx = threadIdx.x; idx < FIN * FH; idx += 256) w1s[idx] = W1[idx];
  __syncthreads();

  const int row_raw = blockIdx.x * 256 + threadIdx.x;
  const int row = row_raw < n ? row_raw : n - 1;
  const float4* __restrict__ xr = (const float4*)(x + (size_t)row * FIN);

  float4 a0 = {0, 0, 0, 0}, a1 = {0, 0, 0, 0}, a2 = {0, 0, 0, 0}, a3 = {0, 0, 0, 0};

#pragma unroll 2
  for (int it = 0; it < FIN / 4; ++it) {
    float4 xv = xr[it];
    const float* wf = w1s + it * 4 * FH;
#pragma unroll
    for (int j = 0; j < 4; ++j) {
      const float xj = (j == 0) ? xv.x : (j == 1) ? xv.y : (j == 2) ? xv.z : xv.w;
      const float* wj = wf + j * FH;
      float4 w0 = *(const float4*)(wj + 0);
      float4 w1 = *(const float4*)(wj + 4);
      float4 w2 = *(const float4*)(wj + 8);
      float4 w3 = *(const float4*)(wj + 12);
      a0.x += xj * w0.x; a0.y += xj * w0.y; a0.z += xj * w0.z; a0.w += xj * w0.w;
      a1.x += xj * w1.x; a1.y += xj * w1.y; a1.z += xj * w1.z; a1.w += xj * w1.w;
      a2.x += xj * w2.x; a2.y += xj * w2.y; a2.z += xj * w2.z; a2.w += xj * w2.w;
      a3.x += xj * w3.x; a3.y += xj * w3.y; a3.z += xj * w3.z; a3.w += xj * w3.w;
    }
  }

  if (row_raw < n) {
    const float di = dinv[row];
    float4* o = (float4*)(hs1 + (size_t)row * FH);
    a0.x *= di; a0.y *= di; a0.z *= di; a0.w *= di;
    a1.x *= di; a1.y *= di; a1.z *= di; a1.w *= di;
    a2.x *= di; a2.y *= di; a2.z *= di; a2.w *= di;
    a3.x *= di; a3.y *= di; a3.z *= di; a3.w *= di;
    o[0] = a0; o[1] = a1; o[2] = a2; o[3] = a3;
  }
}

// ---------- layer-1 gather: LDS-accumulate per dst-range + relu epilogue ----------
__global__ __launch_bounds__(256) void gather1_k(const float* __restrict__ hs1,
                                                 const unsigned* __restrict__ boff,
                                                 const unsigned* __restrict__ bins,
                                                 const float* __restrict__ dinv,
                                                 const float* __restrict__ b1, int n,
                                                 float* __restrict__ rs) {
  __shared__ float acc[RANGE * FH];  // 8 KiB
  __shared__ float b1s[FH];
  const int t = threadIdx.x, b = blockIdx.x;
  if (t < FH) b1s[t] = b1[t];
  for (int u = t; u < RANGE * FH; u += 256) acc[u] = 0.f;
  __syncthreads();
  const unsigned jb = boff[b], je = boff[b + 1];
  const int k = t & 15, slot = t >> 4;
  for (unsigned j = jb + slot; j < je; j += 16) {
    const unsigned pv = bins[j];
    const int s = pv & SRC_MASK;
    const int dl = pv >> SRC_BITS;
    atomicAdd(&acc[dl * FH + k], hs1[(size_t)s * FH + k]);
  }
  __syncthreads();
  const int base = b * RANGE;
  const float4* acc4 = (const float4*)acc;
#pragma unroll
  for (int q = 0; q < 2; ++q) {
    const int fi = t + q * 256;      // [0, 512)
    const int node = fi >> 2, sub = fi & 3;
    const int i = base + node;
    if (i < n) {
      float4 a = acc4[fi];
      float4 hv = ((const float4*)hs1)[(size_t)i * 4 + sub];
      const float d = dinv[i];
      float4 r;
      r.x = (a.x + hv.x) * d + b1s[sub * 4 + 0];
      r.y = (a.y + hv.y) * d + b1s[sub * 4 + 1];
      r.z = (a.z + hv.z) * d + b1s[sub * 4 + 2];
      r.w = (a.w + hv.w) * d + b1s[sub * 4 + 3];
      r.x = (r.x > 0.f ? r.x : 0.f) * d;
      r.y = (r.y > 0.f ? r.y : 0.f) * d;
      r.z = (r.z > 0.f ? r.z : 0.f) * d;
      r.w = (r.w > 0.f ? r.w : 0.f) * d;
      ((float4*)rs)[(size_t)i * 4 + sub] = r;
    }
  }
}

// ---- layer-2: LDS-accumulate + W2 matvec + b2 + log_softmax epilogue ----
__global__ __launch_bounds__(256) void gather2_k(const float* __restrict__ rs,
                                                 const unsigned* __restrict__ boff,
                                                 const unsigned* __restrict__ bins,
                                                 const float* __restrict__ dinv,
                                                 const float* __restrict__ W2,
                                                 const float* __restrict__ b2, int n,
                                                 float* __restrict__ out) {
  __shared__ float acc[RANGE * FH];           // 8 KiB
  __shared__ float w2s[FH * FOUT + FOUT];     // W2 then b2
  const int t = threadIdx.x, b = blockIdx.x;
  for (int idx = t; idx < FH * FOUT + FOUT; idx += 256)
    w2s[idx] = (idx < FH * FOUT) ? W2[idx] : b2[idx - FH * FOUT];
  for (int u = t; u < RANGE * FH; u += 256) acc[u] = 0.f;
  __syncthreads();
  const unsigned jb = boff[b], je = boff[b + 1];
  const int k = t & 15, slot = t >> 4;
  for (unsigned j = jb + slot; j < je; j += 16) {
    const unsigned pv = bins[j];
    const int s = pv & SRC_MASK;
    const int dl = pv >> SRC_BITS;
    atomicAdd(&acc[dl * FH + k], rs[(size_t)s * FH + k]);
  }
  __syncthreads();
  const int base = b * RANGE;
  // phase 1: acc = (acc + rs_self) * dinv  (coalesced)
  float4* acc4 = (float4*)acc;
#pragma unroll
  for (int q = 0; q < 2; ++q) {
    const int fi = t + q * 256;
    const int node = fi >> 2, sub = fi & 3;
    const int i = base + node;
    if (i < n) {
      float4 a = acc4[fi];
      float4 r = ((const float4*)rs)[(size_t)i * 4 + sub];
      const float d = dinv[i];
      a.x = (a.x + r.x) * d;
      a.y = (a.y + r.y) * d;
      a.z = (a.z + r.z) * d;
      a.w = (a.w + r.w) * d;
      acc4[fi] = a;
    }
  }
  __syncthreads();
  // phase 2: per-node 16->40 matvec + log_softmax (4 waves, nodes round-robin)
  const int lane = t & 63, wv = t >> 6;
  for (int nd = wv; nd < RANGE; nd += 4) {
    const int i = base + nd;
    if (i >= n) continue;
    float hv = (lane < FOUT) ? w2s[FH * FOUT + lane] : 0.f;
#pragma unroll
    for (int kk = 0; kk < 16; ++kk) {
      const float a = acc[nd * FH + kk];  // LDS broadcast
      if (lane < FOUT) hv += a * w2s[kk * FOUT + lane];
    }
    float m = (lane < FOUT) ? hv : -INFINITY;
#pragma unroll
    for (int d = 1; d < 64; d <<= 1) m = fmaxf(m, __shfl_xor(m, d));
    float ex = (lane < FOUT) ? expf(hv - m) : 0.f;
#pragma unroll
    for (int d = 1; d < 64; d <<= 1) ex += __shfl_xor(ex, d);
    if (lane < FOUT) out[(size_t)i * FOUT + lane] = hv - m - logf(ex);
  }
}

// ---------------- launch ----------------
extern "C" void kernel_launch(void* const* d_in, const int* in_sizes, int n_in,
                              void* d_out, int out_size, void* d_ws, size_t ws_size,
                              hipStream_t stream) {
  const float* x  = (const float*)d_in[0];
  const int*   ei = (const int*)d_in[1];
  const float* W1 = (const float*)d_in[2];
  const float* b1 = (const float*)d_in[3];
  const float* W2 = (const float*)d_in[4];
  const float* b2 = (const float*)d_in[5];
  float* out = (float*)d_out;

  const int n = in_sizes[0] / FIN;
  const int E = in_sizes[1] / 2;
  const int* src = ei;
  const int* dst = ei + E;
  const int NB = (n + RANGE - 1) >> RSH;

  char* ws = (char*)d_ws;
  size_t o = 0;
  auto alloc = [&](size_t bytes) {
    void* p = ws + o;
    o = (o + bytes + 255) & ~(size_t)255;
    return p;
  };
  unsigned* bcnt = (unsigned*)alloc((size_t)(NB + 1) * 4);
  unsigned* boff = (unsigned*)alloc((size_t)(NB + 1) * 4);
  unsigned* bcur = (unsigned*)alloc((size_t)NB * 4);
  float*    dinv = (float*)alloc((size_t)n * 4);
  unsigned* bins = (unsigned*)alloc((size_t)E * 4);
  float*    hs1  = (float*)alloc((size_t)n * FH * 4);
  float*    rsb  = (float*)alloc((size_t)n * FH * 4);

  hipMemsetAsync(bcnt, 0, (size_t)(NB + 1) * 4, stream);

  histA_k<<<(E + HCHUNK - 1) / HCHUNK, 256, 0, stream>>>(dst, E, NB, bcnt);
  scanB_k<<<1, 1024, 0, stream>>>(bcnt, NB, boff, bcur);
  bin_k<<<(E + BCHUNK - 1) / BCHUNK, 256, 0, stream>>>(src, dst, E, NB, bcur, bins);
  deg_k<<<NB, 256, 0, stream>>>(boff, bins, n, dinv);

  gemm1_k<<<(n + 255) / 256, 256, 0, stream>>>(x, W1, dinv, n, hs1);
  gather1_k<<<NB, 256, 0, stream>>>(hs1, boff, bins, dinv, b1, n, rsb);
  gather2_k<<<NB, 256, 0, stream>>>(rsb, boff, bins, dinv, W2, b2, n, out);
}

// Round 4
// 858.621 us; speedup vs baseline: 1.0292x; 1.0292x over previous
//
#include <hip/hip_runtime.h>
#include <math.h>

#define FIN 512
#define FH 16
#define FOUT 40
#define RANGE 128        // dst nodes per bucket
#define RSH 7
#define NB_MAX 1024      // supports n <= 131072 (also the 17-bit src pack limit)
#define SRC_BITS 17
#define SRC_MASK 0x1FFFF
#define BCHUNK 4096      // edges per bin_k block
#define HCHUNK 16384     // edges per histA block

// ---------- bucket histogram: bcnt[b] = #edges with dst in bucket b ----------
__global__ __launch_bounds__(256) void histA_k(const int* __restrict__ dst, int E, int NB,
                                               unsigned* __restrict__ bcnt) {
  __shared__ unsigned h[NB_MAX];
  for (int b = threadIdx.x; b < NB; b += 256) h[b] = 0;
  __syncthreads();
  const int base = blockIdx.x * HCHUNK;
  const int cn = min(HCHUNK, E - base);
  for (int u = threadIdx.x; u < cn; u += 256)
    atomicAdd(&h[((unsigned)dst[base + u]) >> RSH], 1u);
  __syncthreads();
  for (int b = threadIdx.x; b < NB; b += 256) {
    unsigned c = h[b];
    if (c) atomicAdd(&bcnt[b], c);
  }
}

// ---------- exclusive scan of bucket counts (NB <= 1024, one block) ----------
__global__ __launch_bounds__(1024) void scanB_k(const unsigned* __restrict__ bcnt, int NB,
                                                unsigned* __restrict__ boff,
                                                unsigned* __restrict__ bcur) {
  __shared__ unsigned ws[16];
  const int t = threadIdx.x, lane = t & 63, wid = t >> 6;
  unsigned v = (t < NB) ? bcnt[t] : 0;
  unsigned incl = v;
#pragma unroll
  for (int d = 1; d < 64; d <<= 1) {
    unsigned o = __shfl_up(incl, d);
    if (lane >= d) incl += o;
  }
  if (lane == 63) ws[wid] = incl;
  __syncthreads();
  unsigned woff = 0, tot = 0;
#pragma unroll
  for (int w = 0; w < 16; ++w) {
    unsigned s = ws[w];
    if (w < wid) woff += s;
    tot += s;
  }
  unsigned ex = woff + incl - v;
  if (t < NB) { boff[t] = ex; bcur[t] = ex; }
  if (t == 0) boff[NB] = tot;
}

// ---------- bin edges by bucket: chunk-local counting sort, coalesced flush ----------
__global__ __launch_bounds__(256) void bin_k(const int* __restrict__ src,
                                             const int* __restrict__ dst, int E, int NB,
                                             unsigned* __restrict__ bcur,
                                             unsigned* __restrict__ bins) {
  __shared__ unsigned hist[NB_MAX];
  __shared__ unsigned excl[NB_MAX];
  __shared__ unsigned gbase[NB_MAX];
  __shared__ unsigned lcur[NB_MAX];
  __shared__ unsigned stage[BCHUNK];
  __shared__ unsigned short sbkt[BCHUNK];
  __shared__ unsigned wtot[4];
  const int t = threadIdx.x, lane = t & 63, wid = t >> 6;
  for (int b = t; b < NB; b += 256) hist[b] = 0;
  __syncthreads();
  const int base = blockIdx.x * BCHUNK;
  const int cn = min(BCHUNK, E - base);
  for (int u = t; u < cn; u += 256)
    atomicAdd(&hist[((unsigned)dst[base + u]) >> RSH], 1u);
  __syncthreads();
  // block-wide exclusive scan of hist[0..NB)
  unsigned loc[4], s = 0;
#pragma unroll
  for (int j = 0; j < 4; ++j) {
    int idx = t * 4 + j;
    loc[j] = s;
    s += (idx < NB) ? hist[idx] : 0;
  }
  unsigned incl = s;
#pragma unroll
  for (int d = 1; d < 64; d <<= 1) {
    unsigned o = __shfl_up(incl, d);
    if (lane >= d) incl += o;
  }
  if (lane == 63) wtot[wid] = incl;
  __syncthreads();
  unsigned woff = 0;
  for (int w = 0; w < wid; ++w) woff += wtot[w];
  unsigned tex = woff + incl - s;
#pragma unroll
  for (int j = 0; j < 4; ++j) {
    int idx = t * 4 + j;
    if (idx < NB) excl[idx] = tex + loc[j];
  }
  __syncthreads();
  for (int b = t; b < NB; b += 256) {
    unsigned c = hist[b];
    gbase[b] = c ? atomicAdd(&bcur[b], c) : 0u;
    lcur[b] = excl[b];
  }
  __syncthreads();
  for (int u = t; u < cn; u += 256) {
    int e = base + u;
    unsigned d = (unsigned)dst[e];
    unsigned bkt = d >> RSH;
    unsigned pk = ((unsigned)src[e]) | ((d & (RANGE - 1)) << SRC_BITS);
    unsigned lr = atomicAdd(&lcur[bkt], 1u);
    stage[lr] = pk;
    sbkt[lr] = (unsigned short)bkt;
  }
  __syncthreads();
  for (int u = t; u < cn; u += 256) {
    unsigned bkt = sbkt[u];
    bins[gbase[bkt] + (u - excl[bkt])] = stage[u];
  }
}

// ---------- per-node degree -> dinv, from binned edges (LDS histogram) ----------
__global__ __launch_bounds__(256) void deg_k(const unsigned* __restrict__ boff,
                                             const unsigned* __restrict__ bins, int n,
                                             float* __restrict__ dinv) {
  __shared__ unsigned dh[RANGE];
  const int t = threadIdx.x, b = blockIdx.x;
  if (t < RANGE) dh[t] = 0;
  __syncthreads();
  const unsigned jb = boff[b], je = boff[b + 1];
  for (unsigned j = jb + t; j < je; j += 256) atomicAdd(&dh[bins[j] >> SRC_BITS], 1u);
  __syncthreads();
  const int i = b * RANGE + t;
  if (t < RANGE && i < n) dinv[i] = rsqrtf((float)dh[t] + 1.0f);
}

// ---------------- hs1 = (x @ W1) * dinv[row] ----------------
__global__ __launch_bounds__(256) void gemm1_k(const float* __restrict__ x,
                                               const float* __restrict__ W1,
                                               const float* __restrict__ dinv, int n,
                                               float* __restrict__ hs1) {
  __shared__ float w1s[FIN * FH];  // 32 KiB
  for (int idx = threadIdx.x; idx < FIN * FH; idx += 256) w1s[idx] = W1[idx];
  __syncthreads();

  const int row_raw = blockIdx.x * 256 + threadIdx.x;
  const int row = row_raw < n ? row_raw : n - 1;
  const float4* __restrict__ xr = (const float4*)(x + (size_t)row * FIN);

  float4 a0 = {0, 0, 0, 0}, a1 = {0, 0, 0, 0}, a2 = {0, 0, 0, 0}, a3 = {0, 0, 0, 0};

#pragma unroll 2
  for (int it = 0; it < FIN / 4; ++it) {
    float4 xv = xr[it];
    const float* wf = w1s + it * 4 * FH;
#pragma unroll
    for (int j = 0; j < 4; ++j) {
      const float xj = (j == 0) ? xv.x : (j == 1) ? xv.y : (j == 2) ? xv.z : xv.w;
      const float* wj = wf + j * FH;
      float4 w0 = *(const float4*)(wj + 0);
      float4 w1 = *(const float4*)(wj + 4);
      float4 w2 = *(const float4*)(wj + 8);
      float4 w3 = *(const float4*)(wj + 12);
      a0.x += xj * w0.x; a0.y += xj * w0.y; a0.z += xj * w0.z; a0.w += xj * w0.w;
      a1.x += xj * w1.x; a1.y += xj * w1.y; a1.z += xj * w1.z; a1.w += xj * w1.w;
      a2.x += xj * w2.x; a2.y += xj * w2.y; a2.z += xj * w2.z; a2.w += xj * w2.w;
      a3.x += xj * w3.x; a3.y += xj * w3.y; a3.z += xj * w3.z; a3.w += xj * w3.w;
    }
  }

  if (row_raw < n) {
    const float di = dinv[row];
    float4* o = (float4*)(hs1 + (size_t)row * FH);
    a0.x *= di; a0.y *= di; a0.z *= di; a0.w *= di;
    a1.x *= di; a1.y *= di; a1.z *= di; a1.w *= di;
    a2.x *= di; a2.y *= di; a2.z *= di; a2.w *= di;
    a3.x *= di; a3.y *= di; a3.z *= di; a3.w *= di;
    o[0] = a0; o[1] = a1; o[2] = a2; o[3] = a3;
  }
}

// ---------- layer-1 gather: 512 thr, 32 slots x 4-deep batched edges ----------
__global__ __launch_bounds__(512) void gather1_k(const float* __restrict__ hs1,
                                                 const unsigned* __restrict__ boff,
                                                 const unsigned* __restrict__ bins,
                                                 const float* __restrict__ dinv,
                                                 const float* __restrict__ b1, int n,
                                                 float* __restrict__ rs) {
  __shared__ float acc[RANGE * FH];  // 8 KiB
  __shared__ float b1s[FH];
  const int t = threadIdx.x, b = blockIdx.x;
  if (t < FH) b1s[t] = b1[t];
  for (int u = t; u < RANGE * FH; u += 512) acc[u] = 0.f;
  __syncthreads();
  const unsigned jb = boff[b], je = boff[b + 1];
  const int k = t & 15, slot = t >> 4;  // 32 slots
  unsigned j = jb + slot;
  for (; j + 96 < je; j += 128) {        // 4 independent edges in flight per slot
    const unsigned p0 = bins[j];
    const unsigned p1 = bins[j + 32];
    const unsigned p2 = bins[j + 64];
    const unsigned p3 = bins[j + 96];
    const float v0 = hs1[(size_t)(p0 & SRC_MASK) * FH + k];
    const float v1 = hs1[(size_t)(p1 & SRC_MASK) * FH + k];
    const float v2 = hs1[(size_t)(p2 & SRC_MASK) * FH + k];
    const float v3 = hs1[(size_t)(p3 & SRC_MASK) * FH + k];
    atomicAdd(&acc[(p0 >> SRC_BITS) * FH + k], v0);
    atomicAdd(&acc[(p1 >> SRC_BITS) * FH + k], v1);
    atomicAdd(&acc[(p2 >> SRC_BITS) * FH + k], v2);
    atomicAdd(&acc[(p3 >> SRC_BITS) * FH + k], v3);
  }
  for (; j < je; j += 32) {
    const unsigned p = bins[j];
    atomicAdd(&acc[(p >> SRC_BITS) * FH + k], hs1[(size_t)(p & SRC_MASK) * FH + k]);
  }
  __syncthreads();
  const int base = b * RANGE;
  const float4* acc4 = (const float4*)acc;
  {
    const int fi = t;                 // [0, 512)
    const int node = fi >> 2, sub = fi & 3;
    const int i = base + node;
    if (i < n) {
      float4 a = acc4[fi];
      float4 hv = ((const float4*)hs1)[(size_t)i * 4 + sub];
      const float d = dinv[i];
      float4 r;
      r.x = (a.x + hv.x) * d + b1s[sub * 4 + 0];
      r.y = (a.y + hv.y) * d + b1s[sub * 4 + 1];
      r.z = (a.z + hv.z) * d + b1s[sub * 4 + 2];
      r.w = (a.w + hv.w) * d + b1s[sub * 4 + 3];
      r.x = (r.x > 0.f ? r.x : 0.f) * d;
      r.y = (r.y > 0.f ? r.y : 0.f) * d;
      r.z = (r.z > 0.f ? r.z : 0.f) * d;
      r.w = (r.w > 0.f ? r.w : 0.f) * d;
      ((float4*)rs)[(size_t)i * 4 + sub] = r;
    }
  }
}

// ---- layer-2: 512 thr batched gather + W2 matvec + b2 + log_softmax ----
__global__ __launch_bounds__(512) void gather2_k(const float* __restrict__ rs,
                                                 const unsigned* __restrict__ boff,
                                                 const unsigned* __restrict__ bins,
                                                 const float* __restrict__ dinv,
                                                 const float* __restrict__ W2,
                                                 const float* __restrict__ b2, int n,
                                                 float* __restrict__ out) {
  __shared__ float acc[RANGE * FH];           // 8 KiB
  __shared__ float w2s[FH * FOUT + FOUT];     // W2 then b2
  const int t = threadIdx.x, b = blockIdx.x;
  for (int idx = t; idx < FH * FOUT + FOUT; idx += 512)
    w2s[idx] = (idx < FH * FOUT) ? W2[idx] : b2[idx - FH * FOUT];
  for (int u = t; u < RANGE * FH; u += 512) acc[u] = 0.f;
  __syncthreads();
  const unsigned jb = boff[b], je = boff[b + 1];
  const int k = t & 15, slot = t >> 4;  // 32 slots
  unsigned j = jb + slot;
  for (; j + 96 < je; j += 128) {
    const unsigned p0 = bins[j];
    const unsigned p1 = bins[j + 32];
    const unsigned p2 = bins[j + 64];
    const unsigned p3 = bins[j + 96];
    const float v0 = rs[(size_t)(p0 & SRC_MASK) * FH + k];
    const float v1 = rs[(size_t)(p1 & SRC_MASK) * FH + k];
    const float v2 = rs[(size_t)(p2 & SRC_MASK) * FH + k];
    const float v3 = rs[(size_t)(p3 & SRC_MASK) * FH + k];
    atomicAdd(&acc[(p0 >> SRC_BITS) * FH + k], v0);
    atomicAdd(&acc[(p1 >> SRC_BITS) * FH + k], v1);
    atomicAdd(&acc[(p2 >> SRC_BITS) * FH + k], v2);
    atomicAdd(&acc[(p3 >> SRC_BITS) * FH + k], v3);
  }
  for (; j < je; j += 32) {
    const unsigned p = bins[j];
    atomicAdd(&acc[(p >> SRC_BITS) * FH + k], rs[(size_t)(p & SRC_MASK) * FH + k]);
  }
  __syncthreads();
  const int base = b * RANGE;
  // phase 1: acc = (acc + rs_self) * dinv  (coalesced)
  float4* acc4 = (float4*)acc;
  {
    const int fi = t;
    const int node = fi >> 2, sub = fi & 3;
    const int i = base + node;
    if (i < n) {
      float4 a = acc4[fi];
      float4 r = ((const float4*)rs)[(size_t)i * 4 + sub];
      const float d = dinv[i];
      a.x = (a.x + r.x) * d;
      a.y = (a.y + r.y) * d;
      a.z = (a.z + r.z) * d;
      a.w = (a.w + r.w) * d;
      acc4[fi] = a;
    }
  }
  __syncthreads();
  // phase 2: per-node 16->40 matvec + log_softmax (8 waves, nodes round-robin)
  const int lane = t & 63, wv = t >> 6;
  for (int nd = wv; nd < RANGE; nd += 8) {
    const int i = base + nd;
    if (i >= n) continue;
    float hv = (lane < FOUT) ? w2s[FH * FOUT + lane] : 0.f;
#pragma unroll
    for (int kk = 0; kk < 16; ++kk) {
      const float a = acc[nd * FH + kk];  // LDS broadcast
      if (lane < FOUT) hv += a * w2s[kk * FOUT + lane];
    }
    float m = (lane < FOUT) ? hv : -INFINITY;
#pragma unroll
    for (int d = 1; d < 64; d <<= 1) m = fmaxf(m, __shfl_xor(m, d));
    float ex = (lane < FOUT) ? expf(hv - m) : 0.f;
#pragma unroll
    for (int d = 1; d < 64; d <<= 1) ex += __shfl_xor(ex, d);
    if (lane < FOUT) out[(size_t)i * FOUT + lane] = hv - m - logf(ex);
  }
}

// ---------------- launch ----------------
extern "C" void kernel_launch(void* const* d_in, const int* in_sizes, int n_in,
                              void* d_out, int out_size, void* d_ws, size_t ws_size,
                              hipStream_t stream) {
  const float* x  = (const float*)d_in[0];
  const int*   ei = (const int*)d_in[1];
  const float* W1 = (const float*)d_in[2];
  const float* b1 = (const float*)d_in[3];
  const float* W2 = (const float*)d_in[4];
  const float* b2 = (const float*)d_in[5];
  float* out = (float*)d_out;

  const int n = in_sizes[0] / FIN;
  const int E = in_sizes[1] / 2;
  const int* src = ei;
  const int* dst = ei + E;
  const int NB = (n + RANGE - 1) >> RSH;

  char* ws = (char*)d_ws;
  size_t o = 0;
  auto alloc = [&](size_t bytes) {
    void* p = ws + o;
    o = (o + bytes + 255) & ~(size_t)255;
    return p;
  };
  unsigned* bcnt = (unsigned*)alloc((size_t)(NB + 1) * 4);
  unsigned* boff = (unsigned*)alloc((size_t)(NB + 1) * 4);
  unsigned* bcur = (unsigned*)alloc((size_t)NB * 4);
  float*    dinv = (float*)alloc((size_t)n * 4);
  unsigned* bins = (unsigned*)alloc((size_t)E * 4);
  float*    hs1  = (float*)alloc((size_t)n * FH * 4);
  float*    rsb  = (float*)alloc((size_t)n * FH * 4);

  hipMemsetAsync(bcnt, 0, (size_t)(NB + 1) * 4, stream);

  histA_k<<<(E + HCHUNK - 1) / HCHUNK, 256, 0, stream>>>(dst, E, NB, bcnt);
  scanB_k<<<1, 1024, 0, stream>>>(bcnt, NB, boff, bcur);
  bin_k<<<(E + BCHUNK - 1) / BCHUNK, 256, 0, stream>>>(src, dst, E, NB, bcur, bins);
  deg_k<<<NB, 256, 0, stream>>>(boff, bins, n, dinv);

  gemm1_k<<<(n + 255) / 256, 256, 0, stream>>>(x, W1, dinv, n, hs1);
  gather1_k<<<NB, 512, 0, stream>>>(hs1, boff, bins, dinv, b1, n, rsb);
  gather2_k<<<NB, 512, 0, stream>>>(rsb, boff, bins, dinv, W2, b2, n, out);
}

// Round 5
// 855.075 us; speedup vs baseline: 1.0335x; 1.0041x over previous
//
#include <hip/hip_runtime.h>
#include <hip/hip_fp16.h>
#include <math.h>

#define FIN 512
#define FH 16
#define FOUT 40
#define RANGE 128        // dst nodes per bucket
#define RSH 7
#define NB_MAX 1024      // supports n <= 131072 (also the 17-bit src pack limit)
#define SRC_BITS 17
#define SRC_MASK 0x1FFFF
#define BCHUNK 4096      // edges per bin_k block
#define HCHUNK 16384     // edges per histA block

// ---------- bucket histogram: bcnt[b] = #edges with dst in bucket b ----------
__global__ __launch_bounds__(256) void histA_k(const int* __restrict__ dst, int E, int NB,
                                               unsigned* __restrict__ bcnt) {
  __shared__ unsigned h[NB_MAX];
  for (int b = threadIdx.x; b < NB; b += 256) h[b] = 0;
  __syncthreads();
  const int base = blockIdx.x * HCHUNK;
  const int cn = min(HCHUNK, E - base);
  for (int u = threadIdx.x; u < cn; u += 256)
    atomicAdd(&h[((unsigned)dst[base + u]) >> RSH], 1u);
  __syncthreads();
  for (int b = threadIdx.x; b < NB; b += 256) {
    unsigned c = h[b];
    if (c) atomicAdd(&bcnt[b], c);
  }
}

// ---------- exclusive scan of bucket counts (NB <= 1024, one block) ----------
__global__ __launch_bounds__(1024) void scanB_k(const unsigned* __restrict__ bcnt, int NB,
                                                unsigned* __restrict__ boff,
                                                unsigned* __restrict__ bcur) {
  __shared__ unsigned ws[16];
  const int t = threadIdx.x, lane = t & 63, wid = t >> 6;
  unsigned v = (t < NB) ? bcnt[t] : 0;
  unsigned incl = v;
#pragma unroll
  for (int d = 1; d < 64; d <<= 1) {
    unsigned o = __shfl_up(incl, d);
    if (lane >= d) incl += o;
  }
  if (lane == 63) ws[wid] = incl;
  __syncthreads();
  unsigned woff = 0, tot = 0;
#pragma unroll
  for (int w = 0; w < 16; ++w) {
    unsigned s = ws[w];
    if (w < wid) woff += s;
    tot += s;
  }
  unsigned ex = woff + incl - v;
  if (t < NB) { boff[t] = ex; bcur[t] = ex; }
  if (t == 0) boff[NB] = tot;
}

// ---------- bin edges by bucket: chunk-local counting sort, coalesced flush ----------
__global__ __launch_bounds__(256) void bin_k(const int* __restrict__ src,
                                             const int* __restrict__ dst, int E, int NB,
                                             unsigned* __restrict__ bcur,
                                             unsigned* __restrict__ bins) {
  __shared__ unsigned hist[NB_MAX];
  __shared__ unsigned excl[NB_MAX];
  __shared__ unsigned gbase[NB_MAX];
  __shared__ unsigned lcur[NB_MAX];
  __shared__ unsigned stage[BCHUNK];
  __shared__ unsigned short sbkt[BCHUNK];
  __shared__ unsigned wtot[4];
  const int t = threadIdx.x, lane = t & 63, wid = t >> 6;
  for (int b = t; b < NB; b += 256) hist[b] = 0;
  __syncthreads();
  const int base = blockIdx.x * BCHUNK;
  const int cn = min(BCHUNK, E - base);
  for (int u = t; u < cn; u += 256)
    atomicAdd(&hist[((unsigned)dst[base + u]) >> RSH], 1u);
  __syncthreads();
  // block-wide exclusive scan of hist[0..NB)
  unsigned loc[4], s = 0;
#pragma unroll
  for (int j = 0; j < 4; ++j) {
    int idx = t * 4 + j;
    loc[j] = s;
    s += (idx < NB) ? hist[idx] : 0;
  }
  unsigned incl = s;
#pragma unroll
  for (int d = 1; d < 64; d <<= 1) {
    unsigned o = __shfl_up(incl, d);
    if (lane >= d) incl += o;
  }
  if (lane == 63) wtot[wid] = incl;
  __syncthreads();
  unsigned woff = 0;
  for (int w = 0; w < wid; ++w) woff += wtot[w];
  unsigned tex = woff + incl - s;
#pragma unroll
  for (int j = 0; j < 4; ++j) {
    int idx = t * 4 + j;
    if (idx < NB) excl[idx] = tex + loc[j];
  }
  __syncthreads();
  for (int b = t; b < NB; b += 256) {
    unsigned c = hist[b];
    gbase[b] = c ? atomicAdd(&bcur[b], c) : 0u;
    lcur[b] = excl[b];
  }
  __syncthreads();
  for (int u = t; u < cn; u += 256) {
    int e = base + u;
    unsigned d = (unsigned)dst[e];
    unsigned bkt = d >> RSH;
    unsigned pk = ((unsigned)src[e]) | ((d & (RANGE - 1)) << SRC_BITS);
    unsigned lr = atomicAdd(&lcur[bkt], 1u);
    stage[lr] = pk;
    sbkt[lr] = (unsigned short)bkt;
  }
  __syncthreads();
  for (int u = t; u < cn; u += 256) {
    unsigned bkt = sbkt[u];
    bins[gbase[bkt] + (u - excl[bkt])] = stage[u];
  }
}

// ---------- per-node degree -> dinv, from binned edges (LDS histogram) ----------
__global__ __launch_bounds__(256) void deg_k(const unsigned* __restrict__ boff,
                                             const unsigned* __restrict__ bins, int n,
                                             float* __restrict__ dinv) {
  __shared__ unsigned dh[RANGE];
  const int t = threadIdx.x, b = blockIdx.x;
  if (t < RANGE) dh[t] = 0;
  __syncthreads();
  const unsigned jb = boff[b], je = boff[b + 1];
  for (unsigned j = jb + t; j < je; j += 256) atomicAdd(&dh[bins[j] >> SRC_BITS], 1u);
  __syncthreads();
  const int i = b * RANGE + t;
  if (t < RANGE && i < n) dinv[i] = rsqrtf((float)dh[t] + 1.0f);
}

// ---------------- hs1 = (x @ W1) * dinv[row], stored fp16 ----------------
__global__ __launch_bounds__(256) void gemm1_k(const float* __restrict__ x,
                                               const float* __restrict__ W1,
                                               const float* __restrict__ dinv, int n,
                                               __half* __restrict__ hs1) {
  __shared__ float w1s[FIN * FH];  // 32 KiB
  for (int idx = threadIdx.x; idx < FIN * FH; idx += 256) w1s[idx] = W1[idx];
  __syncthreads();

  const int row_raw = blockIdx.x * 256 + threadIdx.x;
  const int row = row_raw < n ? row_raw : n - 1;
  const float4* __restrict__ xr = (const float4*)(x + (size_t)row * FIN);

  float4 a0 = {0, 0, 0, 0}, a1 = {0, 0, 0, 0}, a2 = {0, 0, 0, 0}, a3 = {0, 0, 0, 0};

#pragma unroll 2
  for (int it = 0; it < FIN / 4; ++it) {
    float4 xv = xr[it];
    const float* wf = w1s + it * 4 * FH;
#pragma unroll
    for (int j = 0; j < 4; ++j) {
      const float xj = (j == 0) ? xv.x : (j == 1) ? xv.y : (j == 2) ? xv.z : xv.w;
      const float* wj = wf + j * FH;
      float4 w0 = *(const float4*)(wj + 0);
      float4 w1 = *(const float4*)(wj + 4);
      float4 w2 = *(const float4*)(wj + 8);
      float4 w3 = *(const float4*)(wj + 12);
      a0.x += xj * w0.x; a0.y += xj * w0.y; a0.z += xj * w0.z; a0.w += xj * w0.w;
      a1.x += xj * w1.x; a1.y += xj * w1.y; a1.z += xj * w1.z; a1.w += xj * w1.w;
      a2.x += xj * w2.x; a2.y += xj * w2.y; a2.z += xj * w2.z; a2.w += xj * w2.w;
      a3.x += xj * w3.x; a3.y += xj * w3.y; a3.z += xj * w3.z; a3.w += xj * w3.w;
    }
  }

  if (row_raw < n) {
    const float di = dinv[row];
    __half2 hb[8];
    hb[0] = __floats2half2_rn(a0.x * di, a0.y * di);
    hb[1] = __floats2half2_rn(a0.z * di, a0.w * di);
    hb[2] = __floats2half2_rn(a1.x * di, a1.y * di);
    hb[3] = __floats2half2_rn(a1.z * di, a1.w * di);
    hb[4] = __floats2half2_rn(a2.x * di, a2.y * di);
    hb[5] = __floats2half2_rn(a2.z * di, a2.w * di);
    hb[6] = __floats2half2_rn(a3.x * di, a3.y * di);
    hb[7] = __floats2half2_rn(a3.z * di, a3.w * di);
    uint4* o = (uint4*)(hs1 + (size_t)row * FH);
    o[0] = ((const uint4*)hb)[0];
    o[1] = ((const uint4*)hb)[1];
  }
}

// ---------- layer-1 gather: fp16 L2-resident table, f32 LDS accumulate ----------
__global__ __launch_bounds__(512) void gather1_k(const __half* __restrict__ hs1,
                                                 const unsigned* __restrict__ boff,
                                                 const unsigned* __restrict__ bins,
                                                 const float* __restrict__ dinv,
                                                 const float* __restrict__ b1, int n,
                                                 __half* __restrict__ rs) {
  __shared__ float acc[RANGE * FH];  // 8 KiB
  __shared__ float b1s[FH];
  const int t = threadIdx.x, b = blockIdx.x;
  if (t < FH) b1s[t] = b1[t];
  for (int u = t; u < RANGE * FH; u += 512) acc[u] = 0.f;
  __syncthreads();
  const unsigned jb = boff[b], je = boff[b + 1];
  const int k = t & 15, slot = t >> 4;  // 32 slots
  unsigned j = jb + slot;
  for (; j + 96 < je; j += 128) {        // 4 independent edges in flight per slot
    const unsigned p0 = bins[j];
    const unsigned p1 = bins[j + 32];
    const unsigned p2 = bins[j + 64];
    const unsigned p3 = bins[j + 96];
    const float v0 = __half2float(hs1[(size_t)(p0 & SRC_MASK) * FH + k]);
    const float v1 = __half2float(hs1[(size_t)(p1 & SRC_MASK) * FH + k]);
    const float v2 = __half2float(hs1[(size_t)(p2 & SRC_MASK) * FH + k]);
    const float v3 = __half2float(hs1[(size_t)(p3 & SRC_MASK) * FH + k]);
    atomicAdd(&acc[(p0 >> SRC_BITS) * FH + k], v0);
    atomicAdd(&acc[(p1 >> SRC_BITS) * FH + k], v1);
    atomicAdd(&acc[(p2 >> SRC_BITS) * FH + k], v2);
    atomicAdd(&acc[(p3 >> SRC_BITS) * FH + k], v3);
  }
  for (; j < je; j += 32) {
    const unsigned p = bins[j];
    atomicAdd(&acc[(p >> SRC_BITS) * FH + k],
              __half2float(hs1[(size_t)(p & SRC_MASK) * FH + k]));
  }
  __syncthreads();
  const int base = b * RANGE;
  const float4* acc4 = (const float4*)acc;
  {
    const int fi = t;                 // [0, 512)
    const int node = fi >> 2, sub = fi & 3;
    const int i = base + node;
    if (i < n) {
      const float4 a = acc4[fi];
      const __half2* hp = (const __half2*)(hs1 + (size_t)i * FH + sub * 4);
      const float2 h0 = __half22float2(hp[0]);
      const float2 h1 = __half22float2(hp[1]);
      const float d = dinv[i];
      float r0 = (a.x + h0.x) * d + b1s[sub * 4 + 0];
      float r1 = (a.y + h0.y) * d + b1s[sub * 4 + 1];
      float r2 = (a.z + h1.x) * d + b1s[sub * 4 + 2];
      float r3 = (a.w + h1.y) * d + b1s[sub * 4 + 3];
      r0 = fmaxf(r0, 0.f) * d;
      r1 = fmaxf(r1, 0.f) * d;
      r2 = fmaxf(r2, 0.f) * d;
      r3 = fmaxf(r3, 0.f) * d;
      __half2* rp = (__half2*)(rs + (size_t)i * FH + sub * 4);
      rp[0] = __floats2half2_rn(r0, r1);
      rp[1] = __floats2half2_rn(r2, r3);
    }
  }
}

// ---- layer-2: fp16 gather + W2 matvec + b2 + log_softmax ----
__global__ __launch_bounds__(512) void gather2_k(const __half* __restrict__ rs,
                                                 const unsigned* __restrict__ boff,
                                                 const unsigned* __restrict__ bins,
                                                 const float* __restrict__ dinv,
                                                 const float* __restrict__ W2,
                                                 const float* __restrict__ b2, int n,
                                                 float* __restrict__ out) {
  __shared__ float acc[RANGE * FH];           // 8 KiB
  __shared__ float w2s[FH * FOUT + FOUT];     // W2 then b2
  const int t = threadIdx.x, b = blockIdx.x;
  for (int idx = t; idx < FH * FOUT + FOUT; idx += 512)
    w2s[idx] = (idx < FH * FOUT) ? W2[idx] : b2[idx - FH * FOUT];
  for (int u = t; u < RANGE * FH; u += 512) acc[u] = 0.f;
  __syncthreads();
  const unsigned jb = boff[b], je = boff[b + 1];
  const int k = t & 15, slot = t >> 4;  // 32 slots
  unsigned j = jb + slot;
  for (; j + 96 < je; j += 128) {
    const unsigned p0 = bins[j];
    const unsigned p1 = bins[j + 32];
    const unsigned p2 = bins[j + 64];
    const unsigned p3 = bins[j + 96];
    const float v0 = __half2float(rs[(size_t)(p0 & SRC_MASK) * FH + k]);
    const float v1 = __half2float(rs[(size_t)(p1 & SRC_MASK) * FH + k]);
    const float v2 = __half2float(rs[(size_t)(p2 & SRC_MASK) * FH + k]);
    const float v3 = __half2float(rs[(size_t)(p3 & SRC_MASK) * FH + k]);
    atomicAdd(&acc[(p0 >> SRC_BITS) * FH + k], v0);
    atomicAdd(&acc[(p1 >> SRC_BITS) * FH + k], v1);
    atomicAdd(&acc[(p2 >> SRC_BITS) * FH + k], v2);
    atomicAdd(&acc[(p3 >> SRC_BITS) * FH + k], v3);
  }
  for (; j < je; j += 32) {
    const unsigned p = bins[j];
    atomicAdd(&acc[(p >> SRC_BITS) * FH + k],
              __half2float(rs[(size_t)(p & SRC_MASK) * FH + k]));
  }
  __syncthreads();
  const int base = b * RANGE;
  // phase 1: acc = (acc + rs_self) * dinv  (coalesced)
  float4* acc4 = (float4*)acc;
  {
    const int fi = t;
    const int node = fi >> 2, sub = fi & 3;
    const int i = base + node;
    if (i < n) {
      float4 a = acc4[fi];
      const __half2* rp = (const __half2*)(rs + (size_t)i * FH + sub * 4);
      const float2 r0 = __half22float2(rp[0]);
      const float2 r1 = __half22float2(rp[1]);
      const float d = dinv[i];
      a.x = (a.x + r0.x) * d;
      a.y = (a.y + r0.y) * d;
      a.z = (a.z + r1.x) * d;
      a.w = (a.w + r1.y) * d;
      acc4[fi] = a;
    }
  }
  __syncthreads();
  // phase 2: per-node 16->40 matvec + log_softmax (8 waves, nodes round-robin)
  const int lane = t & 63, wv = t >> 6;
  for (int nd = wv; nd < RANGE; nd += 8) {
    const int i = base + nd;
    if (i >= n) continue;
    float hv = (lane < FOUT) ? w2s[FH * FOUT + lane] : 0.f;
#pragma unroll
    for (int kk = 0; kk < 16; ++kk) {
      const float a = acc[nd * FH + kk];  // LDS broadcast
      if (lane < FOUT) hv += a * w2s[kk * FOUT + lane];
    }
    float m = (lane < FOUT) ? hv : -INFINITY;
#pragma unroll
    for (int d = 1; d < 64; d <<= 1) m = fmaxf(m, __shfl_xor(m, d));
    float ex = (lane < FOUT) ? expf(hv - m) : 0.f;
#pragma unroll
    for (int d = 1; d < 64; d <<= 1) ex += __shfl_xor(ex, d);
    if (lane < FOUT) out[(size_t)i * FOUT + lane] = hv - m - logf(ex);
  }
}

// ---------------- launch ----------------
extern "C" void kernel_launch(void* const* d_in, const int* in_sizes, int n_in,
                              void* d_out, int out_size, void* d_ws, size_t ws_size,
                              hipStream_t stream) {
  const float* x  = (const float*)d_in[0];
  const int*   ei = (const int*)d_in[1];
  const float* W1 = (const float*)d_in[2];
  const float* b1 = (const float*)d_in[3];
  const float* W2 = (const float*)d_in[4];
  const float* b2 = (const float*)d_in[5];
  float* out = (float*)d_out;

  const int n = in_sizes[0] / FIN;
  const int E = in_sizes[1] / 2;
  const int* src = ei;
  const int* dst = ei + E;
  const int NB = (n + RANGE - 1) >> RSH;

  char* ws = (char*)d_ws;
  size_t o = 0;
  auto alloc = [&](size_t bytes) {
    void* p = ws + o;
    o = (o + bytes + 255) & ~(size_t)255;
    return p;
  };
  unsigned* bcnt = (unsigned*)alloc((size_t)(NB + 1) * 4);
  unsigned* boff = (unsigned*)alloc((size_t)(NB + 1) * 4);
  unsigned* bcur = (unsigned*)alloc((size_t)NB * 4);
  float*    dinv = (float*)alloc((size_t)n * 4);
  unsigned* bins = (unsigned*)alloc((size_t)E * 4);
  __half*   hs1  = (__half*)alloc((size_t)n * FH * 2);
  __half*   rsb  = (__half*)alloc((size_t)n * FH * 2);

  hipMemsetAsync(bcnt, 0, (size_t)(NB + 1) * 4, stream);

  histA_k<<<(E + HCHUNK - 1) / HCHUNK, 256, 0, stream>>>(dst, E, NB, bcnt);
  scanB_k<<<1, 1024, 0, stream>>>(bcnt, NB, boff, bcur);
  bin_k<<<(E + BCHUNK - 1) / BCHUNK, 256, 0, stream>>>(src, dst, E, NB, bcur, bins);
  deg_k<<<NB, 256, 0, stream>>>(boff, bins, n, dinv);

  gemm1_k<<<(n + 255) / 256, 256, 0, stream>>>(x, W1, dinv, n, hs1);
  gather1_k<<<NB, 512, 0, stream>>>(hs1, boff, bins, dinv, b1, n, rsb);
  gather2_k<<<NB, 512, 0, stream>>>(rsb, boff, bins, dinv, W2, b2, n, out);
}